// Round 6
// baseline (19081.073 us; speedup 1.0000x reference)
//
#include <hip/hip_runtime.h>
#include <hip/hip_bf16.h>
#include <stdint.h>

#define T_LEN 1000
#define KIN   69
#define KIN_P 96
#define G3    1536
#define HDIM  512

typedef __attribute__((ext_vector_type(8))) short short8;
typedef __attribute__((ext_vector_type(4))) float f32x4;

#define MFMA(a,b,c) __builtin_amdgcn_mfma_f32_16x16x32_bf16((a),(b),(c),0,0,0)
#define AGENT __HIP_MEMORY_SCOPE_AGENT
#define WG    __HIP_MEMORY_SCOPE_WORKGROUP
#define SPIN_MAX 65536

static __device__ __forceinline__ float sigm(float x){ return 1.0f/(1.0f+__expf(-x)); }
static __device__ __forceinline__ float tanh_f(float x){
  float a = fabsf(x);
  float e = __expf(2.0f*a);
  float t = 1.0f - 2.0f/(e+1.0f);
  return x >= 0.0f ? t : -t;
}
static __device__ __forceinline__ unsigned short f2bf(float f){
  union { float f; unsigned int u; } v; v.f = f;
  unsigned int u = v.u;
  return (unsigned short)((u + 0x7fffu + ((u>>16)&1u)) >> 16);   // RNE
}

// ---------------- sync helpers ----------------
// SLOW (agent/LLC) wait — identical to round-4 protocol.
static __device__ __forceinline__ void wave0_wait(const unsigned int* slots, int np,
                                                  unsigned int target, int lane){
  bool passive = lane >= np;
  int spins = 0;
  for(;;){
    bool d = passive ||
      (__hip_atomic_load(slots + lane*32, __ATOMIC_RELAXED, AGENT) >= target);
    if (__all((int)d)) break;
    if (++spins > SPIN_MAX) break;
  }
  (void)__hip_atomic_load(slots, __ATOMIC_ACQUIRE, WG);
}

// FAST (same-XCD L2) wait: sc0 loads bypass L1, hit the shared L2.
static __device__ __forceinline__ void wave0_wait_fast(const unsigned int* slots, int np,
                                                       unsigned int target, int lane){
  const unsigned int* p = slots + lane*32;
  bool passive = lane >= np;
  int spins = 0;
  for(;;){
    unsigned int v = target;
    if (!passive)
      asm volatile("global_load_dword %0, %1, off sc0\ns_waitcnt vmcnt(0)"
                   : "=v"(v) : "v"(p) : "memory");
    if (__all((int)(v >= target))) break;
    if (++spins > SPIN_MAX) break;
  }
}

#define LD2(r,p,o) asm volatile("global_load_dwordx2 %0, %1, off offset:" o " sc0" : "=v"(r) : "v"(p))
#define ST1(p,v)   asm volatile("global_store_dword %0, %1, off sc0" :: "v"(p), "v"(v) : "memory")
// 32 x 8B h-loads, L1-bypassed, one waitcnt; sched_barrier stops MFMA hoisting (rule #18).
static __device__ __forceinline__ void fast_load_h(const unsigned long long* hrow,
                                                   unsigned long long hv[32]){
  LD2(hv[0],hrow,"0");    LD2(hv[1],hrow,"8");
  LD2(hv[2],hrow,"64");   LD2(hv[3],hrow,"72");
  LD2(hv[4],hrow,"128");  LD2(hv[5],hrow,"136");
  LD2(hv[6],hrow,"192");  LD2(hv[7],hrow,"200");
  LD2(hv[8],hrow,"256");  LD2(hv[9],hrow,"264");
  LD2(hv[10],hrow,"320"); LD2(hv[11],hrow,"328");
  LD2(hv[12],hrow,"384"); LD2(hv[13],hrow,"392");
  LD2(hv[14],hrow,"448"); LD2(hv[15],hrow,"456");
  LD2(hv[16],hrow,"512"); LD2(hv[17],hrow,"520");
  LD2(hv[18],hrow,"576"); LD2(hv[19],hrow,"584");
  LD2(hv[20],hrow,"640"); LD2(hv[21],hrow,"648");
  LD2(hv[22],hrow,"704"); LD2(hv[23],hrow,"712");
  LD2(hv[24],hrow,"768"); LD2(hv[25],hrow,"776");
  LD2(hv[26],hrow,"832"); LD2(hv[27],hrow,"840");
  LD2(hv[28],hrow,"896"); LD2(hv[29],hrow,"904");
  LD2(hv[30],hrow,"960"); LD2(hv[31],hrow,"968");
  asm volatile("s_waitcnt vmcnt(0)" ::: "memory");
  __builtin_amdgcn_sched_barrier(0);
}

// role/mode negotiation: returns role (-1 = exit) and fast flag, consensus via leader.
// gru0: roles 0..31 (dir=role>>4, slice=role&15); FAST iff cnt[xcd0]==32 && cnt[xcd1]==32.
// gru1: roles 0..31 fwd (xcd0), 32..63 bwd (anyone);  FAST iff cnt[xcd0]==32.
static __device__ __forceinline__ void negotiate(unsigned int* ctrl, int kind,
                                                 int* out_role, int* out_fast){
  unsigned int xcc = 0xFFu;
  asm volatile("s_getreg_b32 %0, hwreg(HW_REG_XCC_ID, 0, 32)" : "=s"(xcc));
  xcc &= 0xFu;
  if (xcc < 8u) __hip_atomic_fetch_add(ctrl+1+xcc, 1u, __ATOMIC_RELAXED, AGENT);
  unsigned int my = __hip_atomic_fetch_add(ctrl+0, 1u, __ATOMIC_ACQ_REL, AGENT);
  if (my == 0u){
    int sp = 0;
    while (__hip_atomic_load(ctrl+0, __ATOMIC_ACQUIRE, AGENT) < 256u && ++sp < 600000){}
    unsigned int n0 = __hip_atomic_load(ctrl+1, __ATOMIC_RELAXED, AGENT);
    unsigned int n1 = __hip_atomic_load(ctrl+2, __ATOMIC_RELAXED, AGENT);
    unsigned int fast = (kind == 0) ? ((n0 == 32u && n1 == 32u) ? 1u : 0u)
                                    : ((n0 == 32u) ? 1u : 0u);
    __hip_atomic_store(ctrl+15, 0x80000000u | fast, __ATOMIC_RELEASE, AGENT);
  }
  unsigned int dec; int sp = 0;
  do { dec = __hip_atomic_load(ctrl+15, __ATOMIC_ACQUIRE, AGENT); }
  while (!(dec & 0x80000000u) && ++sp < 4000000);
  int fast = (dec & 0x80000000u) ? (int)(dec & 1u) : 0;
  int role = -1;
  if (kind == 0){
    if (fast){
      if (xcc <= 1u){
        unsigned int t = __hip_atomic_fetch_add(ctrl+9+xcc, 1u, __ATOMIC_RELAXED, AGENT);
        if (t < 16u) role = (int)(xcc*16u + t);
      }
    } else {
      unsigned int t = __hip_atomic_fetch_add(ctrl+11, 1u, __ATOMIC_RELAXED, AGENT);
      if (t < 32u) role = (int)t;
    }
  } else {
    if (fast){
      if (xcc == 0u){
        unsigned int t = __hip_atomic_fetch_add(ctrl+9, 1u, __ATOMIC_RELAXED, AGENT);
        if (t < 32u) role = (int)t;
      }
      if (role < 0){
        unsigned int t = __hip_atomic_fetch_add(ctrl+12, 1u, __ATOMIC_RELAXED, AGENT);
        if (t < 32u) role = 32 + (int)t;
      }
    } else {
      unsigned int t = __hip_atomic_fetch_add(ctrl+11, 1u, __ATOMIC_RELAXED, AGENT);
      if (t < 64u) role = (int)t;
    }
  }
  *out_role = role; *out_fast = fast;
}

// ---------------- small converters ----------------
__global__ void k_conv(const float* __restrict__ src, unsigned short* __restrict__ dst, int n){
  int i = blockIdx.x*256 + threadIdx.x;
  if (i < n) dst[i] = f2bf(src[i]);
}
__global__ void k_conv_pad(const float* __restrict__ src, unsigned short* __restrict__ dst,
                           int rows, int ks, int kd){
  int i = blockIdx.x*256 + threadIdx.x;
  int r = i / kd, c = i % kd;
  if (r < rows) dst[i] = (c < ks) ? f2bf(src[r*ks + c]) : (unsigned short)0;
}
__global__ void k_sentinel(float* __restrict__ out, int n){
  int i = blockIdx.x*256 + threadIdx.x;
  if (i < n) out[i] = 1234.5f;
}

// x: [64][69][1000] f32  ->  xT: [(t*64+b)][96] bf16, zero-padded k 69..95
__global__ void k_xpose(const float* __restrict__ x, unsigned short* __restrict__ xT){
  int b = blockIdx.x & 63, tt = blockIdx.x >> 6;
  int t = tt*64 + threadIdx.x;
  if (t >= T_LEN) return;
  unsigned int* dst = (unsigned int*)(xT + (size_t)(t*64+b)*KIN_P);
  #pragma unroll
  for (int i=0;i<48;i++){
    int k0 = 2*i, k1 = 2*i+1;
    unsigned int lo = (k0<KIN) ? f2bf(x[((size_t)b*KIN + k0)*T_LEN + t]) : 0u;
    unsigned int hi = (k1<KIN) ? f2bf(x[((size_t)b*KIN + k1)*T_LEN + t]) : 0u;
    dst[i] = lo | (hi<<16);
  }
}

// ---------------- layer 0 ----------------
#define NB_B 16
__launch_bounds__(512)
__global__ void k_gru0(const unsigned short* __restrict__ xT,
                       const unsigned short* __restrict__ whh0,
                       const unsigned short* __restrict__ wih0,
                       const float* __restrict__ bih_f, const float* __restrict__ bhh_f,
                       const float* __restrict__ bih_b, const float* __restrict__ bhh_b,
                       unsigned short* __restrict__ l0out,
                       unsigned int* __restrict__ hbuf,    // [2][2][64][256] dwords
                       unsigned int* __restrict__ flags,   // 32 slots x 32 dwords
                       unsigned int* __restrict__ ctrl)
{
  int tid = threadIdx.x;
  int w = tid>>6, l = tid&63;
  __shared__ int sh_role, sh_fast;
  if (tid == 0){
    int role, fast;
    negotiate(ctrl, 0, &role, &fast);
    sh_role = role; sh_fast = fast;
  }
  __syncthreads();
  int role = sh_role, fastm = sh_fast;
  if (role < 0) return;
  int dir = role >> 4;
  int n   = role & 15;
  int j0  = n*32;
  int m0  = (w & 3) * 16;
  int h16 = w >> 2;
  int lj = l & 15, lg = l >> 4;

  __shared__ unsigned char lds[96*1024 + 96*192];
  unsigned char* whh_lds = lds;
  unsigned char* wih_lds = lds + 96*1024;
  const unsigned short* whh_g = whh0 + (size_t)dir*G3*HDIM;
  const unsigned short* wih_g = wih0 + (size_t)dir*G3*KIN_P;

  for (int c = tid; c < 96*64; c += 512){
    int lr = c >> 6, c16 = c & 63;
    int g = lr >> 5, jl = lr & 31;
    int gr = g*512 + j0 + jl;
    uint4 v = *(const uint4*)(whh_g + (size_t)gr*HDIM + c16*8);
    *(uint4*)(whh_lds + lr*1024 + ((c16*16) ^ ((lr&7)<<4))) = v;
  }
  for (int c = tid; c < 96*12; c += 512){
    int lr = c / 12, c16 = c % 12;
    int g = lr >> 5, jl = lr & 31;
    int gr = g*512 + j0 + jl;
    uint4 v = *(const uint4*)(wih_g + (size_t)gr*KIN_P + c16*8);
    *(uint4*)(wih_lds + lr*192 + ((c16*16) ^ ((lr&3)<<4))) = v;
  }
  __syncthreads();

  int jl_mine = h16*16 + lj;
  int jg = j0 + jl_mine;
  const float* bih = dir ? bih_b : bih_f;
  const float* bhh = dir ? bhh_b : bhh_f;
  float brz = bih[jg] + bhh[jg];
  float bzz = bih[512+jg] + bhh[512+jg];
  float bxn = bih[1024+jg];
  float bhn = bhh[1024+jg];
  float hreg[4] = {0.f,0.f,0.f,0.f};
  unsigned int* hb    = hbuf  + (size_t)dir*2*64*256;
  unsigned int* fbase = flags + dir*NB_B*32;
  unsigned int* fmine = fbase + n*32;

  for (int ts = 0; ts < T_LEN; ts++){
    int t = dir ? (T_LEN-1-ts) : ts;
    f32x4 aR={0.f,0.f,0.f,0.f}, aZ={0.f,0.f,0.f,0.f}, aXN={0.f,0.f,0.f,0.f}, aHN={0.f,0.f,0.f,0.f};

    const unsigned short* arow = xT + (size_t)(t*64 + m0 + lj)*KIN_P + lg*8;
    #pragma unroll
    for (int kt=0; kt<3; kt++){
      short8 a = *(const short8*)(arow + kt*32);
      int lr0 = jl_mine, lr1 = 32 + jl_mine, lr2 = 64 + jl_mine;
      int co = kt*64 + lg*16;
      short8 b0 = *(const short8*)(wih_lds + lr0*192 + (co ^ ((lr0&3)<<4)));
      short8 b1 = *(const short8*)(wih_lds + lr1*192 + (co ^ ((lr1&3)<<4)));
      short8 b2 = *(const short8*)(wih_lds + lr2*192 + (co ^ ((lr2&3)<<4)));
      aR  = MFMA(a, b0, aR);
      aZ  = MFMA(a, b1, aZ);
      aXN = MFMA(a, b2, aXN);
    }

    if (ts > 0){
      if (w == 0){
        if (fastm) wave0_wait_fast(fbase, NB_B, (unsigned int)ts, l);
        else       wave0_wait(fbase, NB_B, (unsigned int)ts, l);
      }
      __syncthreads();
    }

    const unsigned long long* hrow = (const unsigned long long*)hb
        + (((ts&1)*64*256 + (m0+lj)*256 + lg*4) >> 1);
    if (fastm){
      unsigned long long hv[32];
      fast_load_h(hrow, hv);
      #pragma unroll
      for (int kt=0; kt<16; kt++){
        union { unsigned long long u[2]; short8 s; } cv;
        cv.u[0] = hv[2*kt]; cv.u[1] = hv[2*kt+1];
        int lr0 = jl_mine, lr1 = 32 + jl_mine, lr2 = 64 + jl_mine;
        int co = kt*64 + lg*16;
        short8 b0 = *(const short8*)(whh_lds + lr0*1024 + (co ^ ((lr0&7)<<4)));
        short8 b1 = *(const short8*)(whh_lds + lr1*1024 + (co ^ ((lr1&7)<<4)));
        short8 b2 = *(const short8*)(whh_lds + lr2*1024 + (co ^ ((lr2&7)<<4)));
        aR  = MFMA(cv.s, b0, aR);
        aZ  = MFMA(cv.s, b1, aZ);
        aHN = MFMA(cv.s, b2, aHN);
      }
    } else {
      #pragma unroll
      for (int kt=0; kt<16; kt++){
        union { unsigned long long u[2]; short8 s; } cv;
        cv.u[0] = __hip_atomic_load(hrow + kt*8 + 0, __ATOMIC_RELAXED, AGENT);
        cv.u[1] = __hip_atomic_load(hrow + kt*8 + 1, __ATOMIC_RELAXED, AGENT);
        int lr0 = jl_mine, lr1 = 32 + jl_mine, lr2 = 64 + jl_mine;
        int co = kt*64 + lg*16;
        short8 b0 = *(const short8*)(whh_lds + lr0*1024 + (co ^ ((lr0&7)<<4)));
        short8 b1 = *(const short8*)(whh_lds + lr1*1024 + (co ^ ((lr1&7)<<4)));
        short8 b2 = *(const short8*)(whh_lds + lr2*1024 + (co ^ ((lr2&7)<<4)));
        aR  = MFMA(cv.s, b0, aR);
        aZ  = MFMA(cv.s, b1, aZ);
        aHN = MFMA(cv.s, b2, aHN);
      }
    }

    float hnew[4];
    #pragma unroll
    for (int i=0;i<4;i++){
      float r = sigm(aR[i] + brz);
      float z = sigm(aZ[i] + bzz);
      float nn = tanh_f(aXN[i] + bxn + r*(aHN[i] + bhn));
      hnew[i] = (1.0f - z)*nn + z*hreg[i];
      hreg[i] = hnew[i];
    }

    unsigned int packed[4];
    #pragma unroll
    for (int i=0;i<4;i++){
      unsigned short mybf = f2bf(hnew[i]);
      unsigned short ot = (unsigned short)__shfl_xor((int)mybf, 1, 64);
      packed[i] = (unsigned int)mybf | ((unsigned int)ot << 16);
    }
    unsigned int* hw = hb + ((ts+1)&1)*64*256;
    if ((l & 1) == 0){
      #pragma unroll
      for (int i=0;i<4;i++){
        int b = m0 + lg*4 + i;
        unsigned int* p = hw + b*256 + (jg>>1);
        if (fastm) ST1(p, packed[i]);
        else __hip_atomic_store(p, packed[i], __ATOMIC_RELAXED, AGENT);
      }
    }
    if (fastm) asm volatile("s_waitcnt vmcnt(0)" ::: "memory"); // drain inline-asm stores
    __syncthreads();
    if (tid == 0){
      if (fastm) ST1(fmine, (unsigned int)(ts+1));
      else __hip_atomic_store(fmine, (unsigned int)(ts+1), __ATOMIC_RELAXED, AGENT);
    }

    // l0out: each wave owns a distinct 16x16 tile -> ALL waves must store (R5 bug fixed)
    #pragma unroll
    for (int i=0;i<4;i++){
      int b = m0 + lg*4 + i;
      l0out[(size_t)(t*64+b)*1024 + dir*512 + jg] = f2bf(hnew[i]);
    }
  }
}

// ---------------- layer 1 ----------------
__launch_bounds__(256)
__global__ void k_gru1(const unsigned short* __restrict__ l0out,
                       const unsigned short* __restrict__ wih1,
                       const unsigned short* __restrict__ whh1f,
                       const float* __restrict__ bih_f, const float* __restrict__ bhh_f,
                       const float* __restrict__ bih_b, const float* __restrict__ bhh_b,
                       float* __restrict__ l1cat,
                       unsigned int* __restrict__ hbuf,    // [2][64][256] dwords
                       unsigned int* __restrict__ flags,   // 32 slots x 32 dwords
                       unsigned int* __restrict__ ctrl)
{
  int tid = threadIdx.x;
  int w = tid>>6, l = tid&63;
  __shared__ int sh_role, sh_fast;
  if (tid == 0){
    int role, fast;
    negotiate(ctrl, 1, &role, &fast);
    sh_role = role; sh_fast = fast;
  }
  __syncthreads();
  int role = sh_role, fastm = sh_fast;
  if (role < 0) return;
  int bwd = role >= 32;
  int n = bwd ? role - 32 : role;
  int j0 = n*16;
  int m0 = w*16, lj = l&15, lg = l>>4;

  __shared__ unsigned char lds[48*2048 + 48*1024];
  unsigned char* wih_lds = lds;
  unsigned char* whh_lds = lds + 48*2048;
  const unsigned short* wih_g = wih1 + (bwd ? (size_t)G3*1024 : 0);

  for (int c = tid; c < 48*128; c += 256){
    int lr = c >> 7, c16 = c & 127;
    int g = lr >> 4, jl = lr & 15;
    int gr = g*512 + j0 + jl;
    uint4 v = *(const uint4*)(wih_g + (size_t)gr*1024 + c16*8);
    *(uint4*)(wih_lds + lr*2048 + ((c16*16) ^ ((lr&7)<<4))) = v;
  }
  if (!bwd){
    for (int c = tid; c < 48*64; c += 256){
      int lr = c >> 6, c16 = c & 63;
      int g = lr >> 4, jl = lr & 15;
      int gr = g*512 + j0 + jl;
      uint4 v = *(const uint4*)(whh1f + (size_t)gr*HDIM + c16*8);
      *(uint4*)(whh_lds + lr*1024 + ((c16*16) ^ ((lr&7)<<4))) = v;
    }
  }
  __syncthreads();

  int jg = j0 + lj;
  const float* bih = bwd ? bih_b : bih_f;
  const float* bhh = bwd ? bhh_b : bhh_f;
  float brz = bih[jg] + bhh[jg];
  float bzz = bih[512+jg] + bhh[512+jg];
  float bxn = bih[1024+jg];
  float bhn = bhh[1024+jg];

  if (bwd){
    int t = T_LEN-1;
    f32x4 aR={0.f,0.f,0.f,0.f}, aZ={0.f,0.f,0.f,0.f}, aXN={0.f,0.f,0.f,0.f};
    const unsigned short* arow = l0out + (size_t)(t*64 + m0 + lj)*1024 + lg*8;
    #pragma unroll 8
    for (int kt=0; kt<32; kt++){
      short8 a = *(const short8*)(arow + kt*32);
      int lr0 = lj, lr1 = 16+lj, lr2 = 32+lj;
      int co = kt*64 + lg*16;
      short8 b0 = *(const short8*)(wih_lds + lr0*2048 + (co ^ ((lr0&7)<<4)));
      short8 b1 = *(const short8*)(wih_lds + lr1*2048 + (co ^ ((lr1&7)<<4)));
      short8 b2 = *(const short8*)(wih_lds + lr2*2048 + (co ^ ((lr2&7)<<4)));
      aR = MFMA(a,b0,aR); aZ = MFMA(a,b1,aZ); aXN = MFMA(a,b2,aXN);
    }
    #pragma unroll
    for (int i=0;i<4;i++){
      float r = sigm(aR[i] + brz);
      float z = sigm(aZ[i] + bzz);
      float nn = tanh_f(aXN[i] + bxn + r*bhn);
      l1cat[(size_t)(m0 + lg*4 + i)*1024 + 512 + jg] = (1.0f - z)*nn;
    }
    return;
  }

  float hreg[4] = {0.f,0.f,0.f,0.f};
  unsigned int* fmine = flags + n*32;
  for (int ts = 0; ts < T_LEN; ts++){
    f32x4 aR={0.f,0.f,0.f,0.f}, aZ={0.f,0.f,0.f,0.f}, aXN={0.f,0.f,0.f,0.f}, aHN={0.f,0.f,0.f,0.f};
    const unsigned short* arow = l0out + (size_t)(ts*64 + m0 + lj)*1024 + lg*8;
    #pragma unroll 8
    for (int kt=0; kt<32; kt++){
      short8 a = *(const short8*)(arow + kt*32);
      int lr0 = lj, lr1 = 16+lj, lr2 = 32+lj;
      int co = kt*64 + lg*16;
      short8 b0 = *(const short8*)(wih_lds + lr0*2048 + (co ^ ((lr0&7)<<4)));
      short8 b1 = *(const short8*)(wih_lds + lr1*2048 + (co ^ ((lr1&7)<<4)));
      short8 b2 = *(const short8*)(wih_lds + lr2*2048 + (co ^ ((lr2&7)<<4)));
      aR = MFMA(a,b0,aR); aZ = MFMA(a,b1,aZ); aXN = MFMA(a,b2,aXN);
    }
    if (ts > 0){
      if (w == 0){
        if (fastm) wave0_wait_fast(flags, 32, (unsigned int)ts, l);
        else       wave0_wait(flags, 32, (unsigned int)ts, l);
      }
      __syncthreads();
    }
    const unsigned long long* hrow = (const unsigned long long*)hbuf
        + (((ts&1)*64*256 + (m0+lj)*256 + lg*4) >> 1);
    if (fastm){
      unsigned long long hv[32];
      fast_load_h(hrow, hv);
      #pragma unroll
      for (int kt=0; kt<16; kt++){
        union { unsigned long long u[2]; short8 s; } cv;
        cv.u[0] = hv[2*kt]; cv.u[1] = hv[2*kt+1];
        int lr0 = lj, lr1 = 16+lj, lr2 = 32+lj;
        int co = kt*64 + lg*16;
        short8 b0 = *(const short8*)(whh_lds + lr0*1024 + (co ^ ((lr0&7)<<4)));
        short8 b1 = *(const short8*)(whh_lds + lr1*1024 + (co ^ ((lr1&7)<<4)));
        short8 b2 = *(const short8*)(whh_lds + lr2*1024 + (co ^ ((lr2&7)<<4)));
        aR = MFMA(cv.s,b0,aR); aZ = MFMA(cv.s,b1,aZ); aHN = MFMA(cv.s,b2,aHN);
      }
    } else {
      #pragma unroll
      for (int kt=0; kt<16; kt++){
        union { unsigned long long u[2]; short8 s; } cv;
        cv.u[0] = __hip_atomic_load(hrow + kt*8 + 0, __ATOMIC_RELAXED, AGENT);
        cv.u[1] = __hip_atomic_load(hrow + kt*8 + 1, __ATOMIC_RELAXED, AGENT);
        int lr0 = lj, lr1 = 16+lj, lr2 = 32+lj;
        int co = kt*64 + lg*16;
        short8 b0 = *(const short8*)(whh_lds + lr0*1024 + (co ^ ((lr0&7)<<4)));
        short8 b1 = *(const short8*)(whh_lds + lr1*1024 + (co ^ ((lr1&7)<<4)));
        short8 b2 = *(const short8*)(whh_lds + lr2*1024 + (co ^ ((lr2&7)<<4)));
        aR = MFMA(cv.s,b0,aR); aZ = MFMA(cv.s,b1,aZ); aHN = MFMA(cv.s,b2,aHN);
      }
    }
    float hnew[4];
    #pragma unroll
    for (int i=0;i<4;i++){
      float r = sigm(aR[i] + brz);
      float z = sigm(aZ[i] + bzz);
      float nn = tanh_f(aXN[i] + bxn + r*(aHN[i] + bhn));
      hnew[i] = (1.0f - z)*nn + z*hreg[i];
      hreg[i] = hnew[i];
    }
    if (ts < T_LEN-1){
      unsigned int packed[4];
      #pragma unroll
      for (int i=0;i<4;i++){
        unsigned short mybf = f2bf(hnew[i]);
        unsigned short ot = (unsigned short)__shfl_xor((int)mybf, 1, 64);
        packed[i] = (unsigned int)mybf | ((unsigned int)ot << 16);
      }
      unsigned int* hw = hbuf + ((ts+1)&1)*64*256;
      if ((l & 1) == 0){
        #pragma unroll
        for (int i=0;i<4;i++){
          int b = m0 + lg*4 + i;
          unsigned int* p = hw + b*256 + (jg>>1);
          if (fastm) ST1(p, packed[i]);
          else __hip_atomic_store(p, packed[i], __ATOMIC_RELAXED, AGENT);
        }
      }
      if (fastm) asm volatile("s_waitcnt vmcnt(0)" ::: "memory");
      __syncthreads();
      if (tid == 0){
        if (fastm) ST1(fmine, (unsigned int)(ts+1));
        else __hip_atomic_store(fmine, (unsigned int)(ts+1), __ATOMIC_RELAXED, AGENT);
      }
    } else {
      #pragma unroll
      for (int i=0;i<4;i++)
        l1cat[(size_t)(m0 + lg*4 + i)*1024 + jg] = hnew[i];
    }
  }
}

// ---------------- final FC ----------------
__global__ void k_fc(const float* __restrict__ l1cat, const float* __restrict__ fcw,
                     const float* __restrict__ fcb, float* __restrict__ out){
  int idx = blockIdx.x*256 + threadIdx.x;
  if (idx >= 64*12) return;
  int b = idx / 12, o = idx % 12;
  float s = fcb[o];
  for (int k=0;k<1024;k++) s += l1cat[b*1024+k]*fcw[o*1024+k];
  out[idx] = s;
}

extern "C" void kernel_launch(void* const* d_in, const int* in_sizes, int n_in,
                              void* d_out, int out_size, void* d_ws, size_t ws_size,
                              hipStream_t stream){
  const float* x     = (const float*)d_in[0];
  const float* wih0f = (const float*)d_in[1];
  const float* whh0f = (const float*)d_in[2];
  const float* bih0f = (const float*)d_in[3];
  const float* bhh0f = (const float*)d_in[4];
  const float* wih0b = (const float*)d_in[5];
  const float* whh0b = (const float*)d_in[6];
  const float* bih0b = (const float*)d_in[7];
  const float* bhh0b = (const float*)d_in[8];
  const float* wih1f = (const float*)d_in[9];
  const float* whh1f = (const float*)d_in[10];
  const float* bih1f = (const float*)d_in[11];
  const float* bhh1f = (const float*)d_in[12];
  const float* wih1b = (const float*)d_in[13];
  const float* bih1b = (const float*)d_in[15];
  const float* bhh1b = (const float*)d_in[16];
  const float* fcw   = (const float*)d_in[17];
  const float* fcb   = (const float*)d_in[18];

  char* ws = (char*)d_ws;
  size_t off = 0;
  auto alloc = [&](size_t bytes)->void*{ void* p = ws + off; off = (off + bytes + 255) & ~(size_t)255; return p; };
  unsigned short* xT    = (unsigned short*)alloc((size_t)64000*96*2);
  unsigned short* whh0c = (unsigned short*)alloc((size_t)2*1536*512*2);
  unsigned short* wih0c = (unsigned short*)alloc((size_t)2*1536*96*2);
  unsigned short* wih1c = (unsigned short*)alloc((size_t)2*1536*1024*2);
  unsigned short* whh1c = (unsigned short*)alloc((size_t)1536*512*2);
  unsigned short* l0out = (unsigned short*)alloc((size_t)64000*1024*2);
  unsigned int*   hbB   = (unsigned int*)alloc((size_t)2*2*64*256*4);
  unsigned int*   hbD   = (unsigned int*)alloc((size_t)2*64*256*4);
  float*          l1cat = (float*)alloc((size_t)64*1024*4);
  unsigned int*   sync  = (unsigned int*)alloc((size_t)4096*4);   // f0|f1|c0|c1

  if (off > ws_size){
    k_sentinel<<<(out_size+255)/256,256,0,stream>>>((float*)d_out, out_size);
    return;
  }

  hipMemsetAsync(hbB, 0, (size_t)2*2*64*256*4, stream);
  hipMemsetAsync(hbD, 0, (size_t)2*64*256*4, stream);
  hipMemsetAsync(sync, 0, (size_t)4096*4, stream);

  k_conv<<<3072,256,0,stream>>>(whh0f, whh0c, 786432);
  k_conv<<<3072,256,0,stream>>>(whh0b, whh0c+786432, 786432);
  k_conv_pad<<<576,256,0,stream>>>(wih0f, wih0c, 1536, 69, 96);
  k_conv_pad<<<576,256,0,stream>>>(wih0b, wih0c+1536*96, 1536, 69, 96);
  k_conv<<<6144,256,0,stream>>>(wih1f, wih1c, 1572864);
  k_conv<<<6144,256,0,stream>>>(wih1b, wih1c+1572864, 1572864);
  k_conv<<<3072,256,0,stream>>>(whh1f, whh1c, 786432);
  k_xpose<<<1024,64,0,stream>>>(x, xT);

  k_gru0<<<256,512,0,stream>>>(xT, whh0c, wih0c, bih0f,bhh0f,bih0b,bhh0b, l0out, hbB,
                               sync, sync + 2048);
  k_gru1<<<256,256,0,stream>>>(l0out, wih1c, whh1c, bih1f,bhh1f,bih1b,bhh1b, l1cat, hbD,
                               sync + 1024, sync + 2112);
  k_fc<<<3,256,0,stream>>>(l1cat, fcw, fcb, (float*)d_out);
}

// Round 8
// 18838.528 us; speedup vs baseline: 1.0129x; 1.0129x over previous
//
#include <hip/hip_runtime.h>
#include <hip/hip_bf16.h>
#include <stdint.h>

#define T_LEN 1000
#define KIN   69
#define KIN_P 96
#define G3    1536
#define HDIM  512
#define POLL_MAX 30000
#define SENT 0xFFFFFFFFu   // bf16 NaN|NaN — unreachable for GRU h in (-1,1)

typedef __attribute__((ext_vector_type(8))) short short8;
typedef __attribute__((ext_vector_type(4))) float f32x4;

#define MFMA(a,b,c) __builtin_amdgcn_mfma_f32_16x16x32_bf16((a),(b),(c),0,0,0)
#define AGENT __HIP_MEMORY_SCOPE_AGENT

static __device__ __forceinline__ float sigm(float x){ return 1.0f/(1.0f+__expf(-x)); }
static __device__ __forceinline__ float tanh_f(float x){
  float a = fabsf(x);
  float e = __expf(2.0f*a);
  float t = 1.0f - 2.0f/(e+1.0f);
  return x >= 0.0f ? t : -t;
}
static __device__ __forceinline__ unsigned short f2bf(float f){
  union { float f; unsigned int u; } v; v.f = f;
  unsigned int u = v.u;
  return (unsigned short)((u + 0x7fffu + ((u>>16)&1u)) >> 16);   // RNE
}

// Poll 16 chunks (16B each) of this thread's h row portion straight from the LLC.
// Freshness = no dword equals SENT. The poll IS the data load (zero extra RTs).
static __device__ __forceinline__ void poll_h(const unsigned long long* h64,
                                              unsigned long long hv[32]){
  unsigned int ok = 0;
  for (int rounds = 0; ok != 0xFFFFu && rounds < POLL_MAX; ++rounds){
    #pragma unroll
    for (int kt=0; kt<16; kt++) if (!(ok & (1u<<kt))){
      hv[2*kt]   = __hip_atomic_load(h64 + kt*8 + 0, __ATOMIC_RELAXED, AGENT);
      hv[2*kt+1] = __hip_atomic_load(h64 + kt*8 + 1, __ATOMIC_RELAXED, AGENT);
    }
    #pragma unroll
    for (int kt=0; kt<16; kt++) if (!(ok & (1u<<kt))){
      unsigned int a = (unsigned int)hv[2*kt],   b = (unsigned int)(hv[2*kt]>>32);
      unsigned int c = (unsigned int)hv[2*kt+1], d = (unsigned int)(hv[2*kt+1]>>32);
      if (a!=SENT && b!=SENT && c!=SENT && d!=SENT) ok |= 1u<<kt;
    }
  }
}

// ---------------- small converters ----------------
__global__ void k_conv(const float* __restrict__ src, unsigned short* __restrict__ dst, int n){
  int i = blockIdx.x*256 + threadIdx.x;
  if (i < n) dst[i] = f2bf(src[i]);
}
__global__ void k_conv_pad(const float* __restrict__ src, unsigned short* __restrict__ dst,
                           int rows, int ks, int kd){
  int i = blockIdx.x*256 + threadIdx.x;
  int r = i / kd, c = i % kd;
  if (r < rows) dst[i] = (c < ks) ? f2bf(src[r*ks + c]) : (unsigned short)0;
}
__global__ void k_sentinel(float* __restrict__ out, int n){
  int i = blockIdx.x*256 + threadIdx.x;
  if (i < n) out[i] = 1234.5f;
}

// x: [64][69][1000] f32  ->  xT: [(t*64+b)][96] bf16
__global__ void k_xpose(const float* __restrict__ x, unsigned short* __restrict__ xT){
  int b = blockIdx.x & 63, tt = blockIdx.x >> 6;
  int t = tt*64 + threadIdx.x;
  if (t >= T_LEN) return;
  unsigned int* dst = (unsigned int*)(xT + (size_t)(t*64+b)*KIN_P);
  #pragma unroll
  for (int i=0;i<48;i++){
    int k0 = 2*i, k1 = 2*i+1;
    unsigned int lo = (k0<KIN) ? f2bf(x[((size_t)b*KIN + k0)*T_LEN + t]) : 0u;
    unsigned int hi = (k1<KIN) ? f2bf(x[((size_t)b*KIN + k1)*T_LEN + t]) : 0u;
    dst[i] = lo | (hi<<16);
  }
}

// ---------------- layer 0: fused input-proj + bidirectional recurrence ----------------
// grid = 32 blocks: dir = bid/16, slice n = bid%16 owns gate cols j in [32n, 32n+32)
// h exchange: 3-slot ring per dir, sentinel-based freshness, NO flags/barriers per step.
#define NB_B 16
__launch_bounds__(512)
__global__ void k_gru0(const unsigned short* __restrict__ xT,
                       const unsigned short* __restrict__ whh0,
                       const unsigned short* __restrict__ wih0,
                       const float* __restrict__ bih_f, const float* __restrict__ bhh_f,
                       const float* __restrict__ bih_b, const float* __restrict__ bhh_b,
                       unsigned short* __restrict__ l0out,
                       unsigned int* __restrict__ hbuf)   // [2][3][64][256] dwords
{
  int bid = blockIdx.x;
  int dir = bid / NB_B;
  int n   = bid % NB_B;
  int j0  = n*32;
  int tid = threadIdx.x;
  int w = tid>>6, l = tid&63;
  int m0  = (w & 3) * 16;
  int h16 = w >> 2;
  int lj = l & 15, lg = l >> 4;

  __shared__ unsigned char lds[96*1024 + 96*192];
  unsigned char* whh_lds = lds;
  unsigned char* wih_lds = lds + 96*1024;
  const unsigned short* whh_g = whh0 + (size_t)dir*G3*HDIM;
  const unsigned short* wih_g = wih0 + (size_t)dir*G3*KIN_P;

  for (int c = tid; c < 96*64; c += 512){
    int lr = c >> 6, c16 = c & 63;
    int g = lr >> 5, jl = lr & 31;
    int gr = g*512 + j0 + jl;
    uint4 v = *(const uint4*)(whh_g + (size_t)gr*HDIM + c16*8);
    *(uint4*)(whh_lds + lr*1024 + ((c16*16) ^ ((lr&7)<<4))) = v;
  }
  for (int c = tid; c < 96*12; c += 512){
    int lr = c / 12, c16 = c % 12;
    int g = lr >> 5, jl = lr & 31;
    int gr = g*512 + j0 + jl;
    uint4 v = *(const uint4*)(wih_g + (size_t)gr*KIN_P + c16*8);
    *(uint4*)(wih_lds + lr*192 + ((c16*16) ^ ((lr&3)<<4))) = v;
  }
  __syncthreads();

  int jl_mine = h16*16 + lj;
  int jg = j0 + jl_mine;
  const float* bih = dir ? bih_b : bih_f;
  const float* bhh = dir ? bhh_b : bhh_f;
  float brz = bih[jg] + bhh[jg];
  float bzz = bih[512+jg] + bhh[512+jg];
  float bxn = bih[1024+jg];
  float bhn = bhh[1024+jg];
  float hreg[4] = {0.f,0.f,0.f,0.f};
  unsigned int* hb = hbuf + (size_t)dir*3*64*256;

  for (int ts = 0; ts < T_LEN; ts++){
    int t = dir ? (T_LEN-1-ts) : ts;
    int s_r = ts % 3, s_w = (ts+1) % 3, s_s = (ts+2) % 3;
    f32x4 aR={0.f,0.f,0.f,0.f}, aZ={0.f,0.f,0.f,0.f}, aXN={0.f,0.f,0.f,0.f}, aHN={0.f,0.f,0.f,0.f};

    // input-projection (independent of h)
    const unsigned short* arow = xT + (size_t)(t*64 + m0 + lj)*KIN_P + lg*8;
    #pragma unroll
    for (int kt=0; kt<3; kt++){
      short8 a = *(const short8*)(arow + kt*32);
      int lr0 = jl_mine, lr1 = 32 + jl_mine, lr2 = 64 + jl_mine;
      int co = kt*64 + lg*16;
      short8 b0 = *(const short8*)(wih_lds + lr0*192 + (co ^ ((lr0&3)<<4)));
      short8 b1 = *(const short8*)(wih_lds + lr1*192 + (co ^ ((lr1&3)<<4)));
      short8 b2 = *(const short8*)(wih_lds + lr2*192 + (co ^ ((lr2&3)<<4)));
      aR  = MFMA(a, b0, aR);
      aZ  = MFMA(a, b1, aZ);
      aXN = MFMA(a, b2, aXN);
    }

    // poll h(ts) directly (self-announcing data; ts=0 slot holds zeros = fresh)
    unsigned long long hv[32];
    const unsigned long long* h64 = (const unsigned long long*)(hb + s_r*64*256)
        + ((((m0+lj)*256) + lg*4) >> 1);
    poll_h(h64, hv);

    #pragma unroll
    for (int kt=0; kt<16; kt++){
      union { unsigned long long u[2]; short8 s; } cv;
      cv.u[0] = hv[2*kt]; cv.u[1] = hv[2*kt+1];
      int lr0 = jl_mine, lr1 = 32 + jl_mine, lr2 = 64 + jl_mine;
      int co = kt*64 + lg*16;
      short8 b0 = *(const short8*)(whh_lds + lr0*1024 + (co ^ ((lr0&7)<<4)));
      short8 b1 = *(const short8*)(whh_lds + lr1*1024 + (co ^ ((lr1&7)<<4)));
      short8 b2 = *(const short8*)(whh_lds + lr2*1024 + (co ^ ((lr2&7)<<4)));
      aR  = MFMA(cv.s, b0, aR);
      aZ  = MFMA(cv.s, b1, aZ);
      aHN = MFMA(cv.s, b2, aHN);
    }

    float hnew[4];
    #pragma unroll
    for (int i=0;i<4;i++){
      float r = sigm(aR[i] + brz);
      float z = sigm(aZ[i] + bzz);
      float nn = tanh_f(aXN[i] + bxn + r*(aHN[i] + bhn));
      hnew[i] = (1.0f - z)*nn + z*hreg[i];
      hreg[i] = hnew[i];
    }

    if (ts < T_LEN-1){
      // re-sentinel my region of slot ts+2 (safe: same-row readers provably done),
      // then publish h(ts+1) into slot ts+1. No barriers, no flags.
      unsigned int packed[4];
      #pragma unroll
      for (int i=0;i<4;i++){
        unsigned short mybf = f2bf(hnew[i]);
        unsigned short ot = (unsigned short)__shfl_xor((int)mybf, 1, 64);
        packed[i] = (unsigned int)mybf | ((unsigned int)ot << 16);
      }
      if ((l & 1) == 0){
        unsigned int* hs = hb + s_s*64*256;
        unsigned int* hw = hb + s_w*64*256;
        #pragma unroll
        for (int i=0;i<4;i++){
          int b = m0 + lg*4 + i;
          __hip_atomic_store(hs + b*256 + (jg>>1), SENT, __ATOMIC_RELAXED, AGENT);
          __hip_atomic_store(hw + b*256 + (jg>>1), packed[i], __ATOMIC_RELAXED, AGENT);
        }
      }
    }

    #pragma unroll
    for (int i=0;i<4;i++){
      int b = m0 + lg*4 + i;
      l0out[(size_t)(t*64+b)*1024 + dir*512 + jg] = f2bf(hnew[i]);
    }
  }
}

// ---------------- layer 1: fused input-proj + fwd recurrence; bwd is ONE step ----------------
__launch_bounds__(256)
__global__ void k_gru1(const unsigned short* __restrict__ l0out,
                       const unsigned short* __restrict__ wih1,
                       const unsigned short* __restrict__ whh1f,
                       const float* __restrict__ bih_f, const float* __restrict__ bhh_f,
                       const float* __restrict__ bih_b, const float* __restrict__ bhh_b,
                       float* __restrict__ l1cat,
                       unsigned int* __restrict__ hbuf)   // [3][64][256] dwords
{
  int bid = blockIdx.x;
  int bwd = bid >= 32;
  int n = bwd ? bid - 32 : bid;
  int j0 = n*16;
  int tid = threadIdx.x;
  int w = tid>>6, l = tid&63;
  int m0 = w*16, lj = l&15, lg = l>>4;

  __shared__ unsigned char lds[48*2048 + 48*1024];
  unsigned char* wih_lds = lds;
  unsigned char* whh_lds = lds + 48*2048;
  const unsigned short* wih_g = wih1 + (bwd ? (size_t)G3*1024 : 0);

  for (int c = tid; c < 48*128; c += 256){
    int lr = c >> 7, c16 = c & 127;
    int g = lr >> 4, jl = lr & 15;
    int gr = g*512 + j0 + jl;
    uint4 v = *(const uint4*)(wih_g + (size_t)gr*1024 + c16*8);
    *(uint4*)(wih_lds + lr*2048 + ((c16*16) ^ ((lr&7)<<4))) = v;
  }
  if (!bwd){
    for (int c = tid; c < 48*64; c += 256){
      int lr = c >> 6, c16 = c & 63;
      int g = lr >> 4, jl = lr & 15;
      int gr = g*512 + j0 + jl;
      uint4 v = *(const uint4*)(whh1f + (size_t)gr*HDIM + c16*8);
      *(uint4*)(whh_lds + lr*1024 + ((c16*16) ^ ((lr&7)<<4))) = v;
    }
  }
  __syncthreads();

  int jg = j0 + lj;
  const float* bih = bwd ? bih_b : bih_f;
  const float* bhh = bwd ? bhh_b : bhh_f;
  float brz = bih[jg] + bhh[jg];
  float bzz = bih[512+jg] + bhh[512+jg];
  float bxn = bih[1024+jg];
  float bhn = bhh[1024+jg];

  if (bwd){
    int t = T_LEN-1;
    f32x4 aR={0.f,0.f,0.f,0.f}, aZ={0.f,0.f,0.f,0.f}, aXN={0.f,0.f,0.f,0.f};
    const unsigned short* arow = l0out + (size_t)(t*64 + m0 + lj)*1024 + lg*8;
    #pragma unroll 8
    for (int kt=0; kt<32; kt++){
      short8 a = *(const short8*)(arow + kt*32);
      int lr0 = lj, lr1 = 16+lj, lr2 = 32+lj;
      int co = kt*64 + lg*16;
      short8 b0 = *(const short8*)(wih_lds + lr0*2048 + (co ^ ((lr0&7)<<4)));
      short8 b1 = *(const short8*)(wih_lds + lr1*2048 + (co ^ ((lr1&7)<<4)));
      short8 b2 = *(const short8*)(wih_lds + lr2*2048 + (co ^ ((lr2&7)<<4)));
      aR = MFMA(a,b0,aR); aZ = MFMA(a,b1,aZ); aXN = MFMA(a,b2,aXN);
    }
    #pragma unroll
    for (int i=0;i<4;i++){
      float r = sigm(aR[i] + brz);
      float z = sigm(aZ[i] + bzz);
      float nn = tanh_f(aXN[i] + bxn + r*bhn);
      l1cat[(size_t)(m0 + lg*4 + i)*1024 + 512 + jg] = (1.0f - z)*nn;
    }
    return;
  }

  float hreg[4] = {0.f,0.f,0.f,0.f};
  for (int ts = 0; ts < T_LEN; ts++){
    int s_r = ts % 3, s_w = (ts+1) % 3, s_s = (ts+2) % 3;
    f32x4 aR={0.f,0.f,0.f,0.f}, aZ={0.f,0.f,0.f,0.f}, aXN={0.f,0.f,0.f,0.f}, aHN={0.f,0.f,0.f,0.f};
    const unsigned short* arow = l0out + (size_t)(ts*64 + m0 + lj)*1024 + lg*8;
    #pragma unroll 8
    for (int kt=0; kt<32; kt++){
      short8 a = *(const short8*)(arow + kt*32);
      int lr0 = lj, lr1 = 16+lj, lr2 = 32+lj;
      int co = kt*64 + lg*16;
      short8 b0 = *(const short8*)(wih_lds + lr0*2048 + (co ^ ((lr0&7)<<4)));
      short8 b1 = *(const short8*)(wih_lds + lr1*2048 + (co ^ ((lr1&7)<<4)));
      short8 b2 = *(const short8*)(wih_lds + lr2*2048 + (co ^ ((lr2&7)<<4)));
      aR = MFMA(a,b0,aR); aZ = MFMA(a,b1,aZ); aXN = MFMA(a,b2,aXN);
    }

    unsigned long long hv[32];
    const unsigned long long* h64 = (const unsigned long long*)(hbuf + s_r*64*256)
        + ((((m0+lj)*256) + lg*4) >> 1);
    poll_h(h64, hv);

    #pragma unroll
    for (int kt=0; kt<16; kt++){
      union { unsigned long long u[2]; short8 s; } cv;
      cv.u[0] = hv[2*kt]; cv.u[1] = hv[2*kt+1];
      int lr0 = lj, lr1 = 16+lj, lr2 = 32+lj;
      int co = kt*64 + lg*16;
      short8 b0 = *(const short8*)(whh_lds + lr0*1024 + (co ^ ((lr0&7)<<4)));
      short8 b1 = *(const short8*)(whh_lds + lr1*1024 + (co ^ ((lr1&7)<<4)));
      short8 b2 = *(const short8*)(whh_lds + lr2*1024 + (co ^ ((lr2&7)<<4)));
      aR = MFMA(cv.s,b0,aR); aZ = MFMA(cv.s,b1,aZ); aHN = MFMA(cv.s,b2,aHN);
    }
    float hnew[4];
    #pragma unroll
    for (int i=0;i<4;i++){
      float r = sigm(aR[i] + brz);
      float z = sigm(aZ[i] + bzz);
      float nn = tanh_f(aXN[i] + bxn + r*(aHN[i] + bhn));
      hnew[i] = (1.0f - z)*nn + z*hreg[i];
      hreg[i] = hnew[i];
    }
    if (ts < T_LEN-1){
      unsigned int packed[4];
      #pragma unroll
      for (int i=0;i<4;i++){
        unsigned short mybf = f2bf(hnew[i]);
        unsigned short ot = (unsigned short)__shfl_xor((int)mybf, 1, 64);
        packed[i] = (unsigned int)mybf | ((unsigned int)ot << 16);
      }
      if ((l & 1) == 0){
        unsigned int* hs = hbuf + s_s*64*256;
        unsigned int* hw = hbuf + s_w*64*256;
        #pragma unroll
        for (int i=0;i<4;i++){
          int b = m0 + lg*4 + i;
          __hip_atomic_store(hs + b*256 + (jg>>1), SENT, __ATOMIC_RELAXED, AGENT);
          __hip_atomic_store(hw + b*256 + (jg>>1), packed[i], __ATOMIC_RELAXED, AGENT);
        }
      }
    } else {
      #pragma unroll
      for (int i=0;i<4;i++)
        l1cat[(size_t)(m0 + lg*4 + i)*1024 + jg] = hnew[i];
    }
  }
}

// ---------------- final FC ----------------
__global__ void k_fc(const float* __restrict__ l1cat, const float* __restrict__ fcw,
                     const float* __restrict__ fcb, float* __restrict__ out){
  int idx = blockIdx.x*256 + threadIdx.x;
  if (idx >= 64*12) return;
  int b = idx / 12, o = idx % 12;
  float s = fcb[o];
  for (int k=0;k<1024;k++) s += l1cat[b*1024+k]*fcw[o*1024+k];
  out[idx] = s;
}

extern "C" void kernel_launch(void* const* d_in, const int* in_sizes, int n_in,
                              void* d_out, int out_size, void* d_ws, size_t ws_size,
                              hipStream_t stream){
  const float* x     = (const float*)d_in[0];
  const float* wih0f = (const float*)d_in[1];
  const float* whh0f = (const float*)d_in[2];
  const float* bih0f = (const float*)d_in[3];
  const float* bhh0f = (const float*)d_in[4];
  const float* wih0b = (const float*)d_in[5];
  const float* whh0b = (const float*)d_in[6];
  const float* bih0b = (const float*)d_in[7];
  const float* bhh0b = (const float*)d_in[8];
  const float* wih1f = (const float*)d_in[9];
  const float* whh1f = (const float*)d_in[10];
  const float* bih1f = (const float*)d_in[11];
  const float* bhh1f = (const float*)d_in[12];
  const float* wih1b = (const float*)d_in[13];
  const float* bih1b = (const float*)d_in[15];
  const float* bhh1b = (const float*)d_in[16];
  const float* fcw   = (const float*)d_in[17];
  const float* fcb   = (const float*)d_in[18];

  const size_t SLOT = (size_t)64*256*4;   // 64 KB per ring slot

  char* ws = (char*)d_ws;
  size_t off = 0;
  auto alloc = [&](size_t bytes)->void*{ void* p = ws + off; off = (off + bytes + 255) & ~(size_t)255; return p; };
  unsigned short* xT    = (unsigned short*)alloc((size_t)64000*96*2);
  unsigned short* whh0c = (unsigned short*)alloc((size_t)2*1536*512*2);
  unsigned short* wih0c = (unsigned short*)alloc((size_t)2*1536*96*2);
  unsigned short* wih1c = (unsigned short*)alloc((size_t)2*1536*1024*2);
  unsigned short* whh1c = (unsigned short*)alloc((size_t)1536*512*2);
  unsigned short* l0out = (unsigned short*)alloc((size_t)64000*1024*2);
  unsigned int*   hbB   = (unsigned int*)alloc((size_t)2*3*SLOT);   // [2][3][64][256]
  unsigned int*   hbD   = (unsigned int*)alloc((size_t)3*SLOT);     // [3][64][256]
  float*          l1cat = (float*)alloc((size_t)64*1024*4);

  if (off > ws_size){
    k_sentinel<<<(out_size+255)/256,256,0,stream>>>((float*)d_out, out_size);
    return;
  }

  // ring init: slot 0 = zeros (h0 = 0), slots 1..2 = 0xFF sentinel bytes
  for (int d = 0; d < 2; d++){
    char* base = (char*)hbB + (size_t)d*3*SLOT;
    hipMemsetAsync(base, 0, SLOT, stream);
    hipMemsetAsync(base + SLOT, 0xFF, 2*SLOT, stream);
  }
  hipMemsetAsync(hbD, 0, SLOT, stream);
  hipMemsetAsync((char*)hbD + SLOT, 0xFF, 2*SLOT, stream);

  k_conv<<<3072,256,0,stream>>>(whh0f, whh0c, 786432);
  k_conv<<<3072,256,0,stream>>>(whh0b, whh0c+786432, 786432);
  k_conv_pad<<<576,256,0,stream>>>(wih0f, wih0c, 1536, 69, 96);
  k_conv_pad<<<576,256,0,stream>>>(wih0b, wih0c+1536*96, 1536, 69, 96);
  k_conv<<<6144,256,0,stream>>>(wih1f, wih1c, 1572864);
  k_conv<<<6144,256,0,stream>>>(wih1b, wih1c+1572864, 1572864);
  k_conv<<<3072,256,0,stream>>>(whh1f, whh1c, 786432);
  k_xpose<<<1024,64,0,stream>>>(x, xT);

  k_gru0<<<32,512,0,stream>>>(xT, whh0c, wih0c, bih0f,bhh0f,bih0b,bhh0b, l0out, hbB);
  k_gru1<<<64,256,0,stream>>>(l0out, wih1c, whh1c, bih1f,bhh1f,bih1b,bhh1b, l1cat, hbD);
  k_fc<<<3,256,0,stream>>>(l1cat, fcw, fcb, (float*)d_out);
}